// Round 13
// baseline (147.465 us; speedup 1.0000x reference)
//
#include <hip/hip_runtime.h>

#define OUT_MU 131072
#define OUT_OM 262144
#define WOUT_OFF 4210688              // half-index of packed W_out

typedef _Float16 half8 __attribute__((ext_vector_type(8)));
typedef __fp16   fp16x2 __attribute__((ext_vector_type(2)));
typedef float    floatx4 __attribute__((ext_vector_type(4)));
typedef unsigned uint2v __attribute__((ext_vector_type(2)));

__device__ __forceinline__ void wait_lgkm0() {
    asm volatile("s_waitcnt lgkmcnt(0)" ::: "memory");
}
__device__ __forceinline__ void wait_vm0() {
    asm volatile("s_waitcnt vmcnt(0)" ::: "memory");
}
__device__ __forceinline__ void barrier_raw() {
    asm volatile("s_barrier" ::: "memory");
}

#define AS1 __attribute__((address_space(1)))
#define AS3 __attribute__((address_space(3)))

// ---------------------------------------------------------------------------
// Repack hidden weights fp32 -> fp16 as
//   [ch(16)][g(32)][wv(4)][nt(4)][ks(4)][r16(16)][e(8)]   (half8 units)
// A-frag (16x16x32_f16): lane l holds row n = nt*16 + (l&15),
//                        k = (g&7)*32 + (l>>4)*8 + e.   (unchanged, verified)
// ---------------------------------------------------------------------------
__global__ void prep_w(const float* __restrict__ Wr_h,
                       const float* __restrict__ Wc_h,
                       _Float16* __restrict__ dst) {
    int v = blockIdx.x * 256 + threadIdx.x;        // 524288 half8 slots
    int r16 = v & 15;
    int ks  = (v >> 4) & 3;
    int nt  = (v >> 6) & 3;
    int wv  = (v >> 8) & 3;
    int g   = (v >> 10) & 31;
    int ch  = v >> 15;
    int l = g >> 3, kk = g & 7;
    int n  = wv * 64 + nt * 16 + r16;
    int k0 = kk * 32 + ks * 8;
    const float* src = (ch < 8) ? Wr_h : Wc_h;
    int c = ch & 7;
    const float* p = src + ((size_t)((l * 8 + c) * 256 + n)) * 256 + k0;
    float4 a = *(const float4*)p;
    float4 b = *(const float4*)(p + 4);
    half8 o;
    o[0] = (_Float16)a.x; o[1] = (_Float16)a.y; o[2] = (_Float16)a.z; o[3] = (_Float16)a.w;
    o[4] = (_Float16)b.x; o[5] = (_Float16)b.y; o[6] = (_Float16)b.z; o[7] = (_Float16)b.w;
    *(half8*)(dst + (size_t)v * 8) = o;
}

// W_out pack: [ch(16)][d(2)][j(256)] fp16 (real channels use d=0 only).
__global__ void prep_wo(const float* __restrict__ Wr_out,
                        const float* __restrict__ Wc_out,
                        _Float16* __restrict__ dst) {
    int t = blockIdx.x * 256 + threadIdx.x;        // 8192
    int j = t & 255, d = (t >> 8) & 1, ch = t >> 9;
    int c = ch & 7;
    float v;
    if (ch < 8) v = d ? 0.f : Wr_out[c * 256 + j];
    else        v = Wc_out[(c * 2 + d) * 256 + j];
    dst[WOUT_OFF + t] = (_Float16)v;
}

// ---------------------------------------------------------------------------
// One pipeline phase: K-loop for HALF (rows HALF*64..+63, 128 MFMA) with the
// OTHER half's layer epilogue (bias+relu+cvt+ds_write, 16 units) interleaved
// into the MFMA shadow (2 units per kk step). Weights register-double-
// buffered; bfr depth-1 (16-MFMA shadow >> 120cyc LDS latency).
// ---------------------------------------------------------------------------
template<int HALF, int EPIHALF, bool DO_EPI>
__device__ __forceinline__ void run_phase(char* __restrict__ smem, int vbase,
        const half8* __restrict__ wlg, const half8* __restrict__ wlg_next,
        const float* __restrict__ bh_epi,
        half8 (&wreg)[2][4],
        floatx4 (&acc)[4][4], floatx4 (&eacc)[4][4],
        int wv, int ks, int r16) {
    // bias for the epi drained this phase (latency hidden under first MFMAs)
    float4 eb[4];
    if (DO_EPI) {
        #pragma unroll
        for (int nt = 0; nt < 4; ++nt) eb[nt] = *(const float4*)(bh_epi + nt * 16);
    }
    #pragma unroll
    for (int a = 0; a < 4; ++a)
        #pragma unroll
        for (int b = 0; b < 4; ++b) acc[a][b] = 0.f;

    const int hb = HALF * 32768;
    half8 bfr[2][4];
    #pragma unroll
    for (int j = 0; j < 4; ++j)
        bfr[0][j] = *(const half8*)(smem + vbase + hb + j * 8192);

    #pragma unroll
    for (int kk = 0; kk < 8; ++kk) {
        {   // weight prefetch kk+1 (kk=7 -> next phase's kk=0)
            const half8* wp = (kk < 7 ? wlg : wlg_next) + ((kk + 1) & 7) * 1024;
            #pragma unroll
            for (int nt = 0; nt < 4; ++nt) wreg[(kk + 1) & 1][nt] = wp[nt * 64];
        }
        if (kk < 7) {                               // activation prefetch
            const char* nbp = smem + ((vbase ^ ((kk + 1) << 6)) + hb);
            #pragma unroll
            for (int j = 0; j < 4; ++j)
                bfr[(kk + 1) & 1][j] = *(const half8*)(nbp + j * 8192);
        }
        __builtin_amdgcn_s_setprio(1);
        #pragma unroll
        for (int nt = 0; nt < 2; ++nt)
            #pragma unroll
            for (int mt = 0; mt < 4; ++mt)
                acc[nt][mt] = __builtin_amdgcn_mfma_f32_16x16x32_f16(
                    wreg[kk & 1][nt], bfr[kk & 1][mt], acc[nt][mt], 0, 0, 0);
        __builtin_amdgcn_s_setprio(0);
        if (DO_EPI) {                               // 2 epi units in MFMA shadow
            #pragma unroll
            for (int c2 = 0; c2 < 2; ++c2) {
                const int u = 2 * kk + c2, nt = u >> 2, mt = u & 3;
                floatx4 v = eacc[nt][mt];
                float4 b = eb[nt];
                union { fp16x2 h; unsigned u32; } c0, c1;
                c0.h = __builtin_amdgcn_cvt_pkrtz(fmaxf(v[0] + b.x, 0.f),
                                                  fmaxf(v[1] + b.y, 0.f));
                c1.h = __builtin_amdgcn_cvt_pkrtz(fmaxf(v[2] + b.z, 0.f),
                                                  fmaxf(v[3] + b.w, 0.f));
                const int nb = wv * 64 + nt * 16 + ks * 4;
                const int m = EPIHALF * 64 + mt * 16 + r16;
                uint2v o; o[0] = c0.u32; o[1] = c1.u32;
                *(uint2v*)(smem + m * 512 + (((nb >> 3) << 4) ^ ((r16 & 7) << 4))
                           + (nb & 7) * 2) = o;
            }
        }
        __builtin_amdgcn_s_setprio(1);
        #pragma unroll
        for (int nt = 2; nt < 4; ++nt)
            #pragma unroll
            for (int mt = 0; mt < 4; ++mt)
                acc[nt][mt] = __builtin_amdgcn_mfma_f32_16x16x32_f16(
                    wreg[kk & 1][nt], bfr[kk & 1][mt], acc[nt][mt], 0, 0, 0);
        __builtin_amdgcn_s_setprio(0);
    }
}

// ---------------------------------------------------------------------------
// Fused MLP, 16x16x32_f16, 4 waves, 128-row tile, HALF-TILE SOFTWARE PIPELINE:
// P0=K(A,0); P(2t+1)=K(B,t)+epi(A,t); P(2t+2)=K(A,t+1)+epi(B,t); P8=epi(B,3).
// Every phase carries 128 MFMA -> no joint MFMA-idle windows across the two
// co-resident blocks. h (128x256 swizzled) + z in LDS; weights global->VGPR.
// ---------------------------------------------------------------------------
__global__ __launch_bounds__(256, 2)
void mlp_fused(const float* __restrict__ z,
               const float* __restrict__ Wr_in, const float* __restrict__ br_in,
               const float* __restrict__ Wc_in, const float* __restrict__ bc_in,
               const float* __restrict__ br_h,  const float* __restrict__ bc_h,
               const float* __restrict__ br_out, const float* __restrict__ bc_out,
               const _Float16* __restrict__ wst,
               float* __restrict__ out) {
    __shared__ __align__(16) char smem[77824];     // [0,64K)=h, [64K,76K)=z
    const int tid  = threadIdx.x;
    const int lane = tid & 63;
    const int wv   = tid >> 6;
    const int bid  = blockIdx.x;
    const int ch   = bid & 15;
    const int m0   = (bid >> 4) * 128;
    const bool isC = ch >= 8;
    const int c    = ch & 7;
    const int ks   = lane >> 4;
    const int r16  = lane & 15;
    float* zbuf = (float*)(smem + 65536);

    // ---- stage z tile (wave wv stages rows [wv*32, wv*32+32)) ----
    {
        const float* zs = z + (size_t)m0 * 24 + wv * 768 + lane * 4;
        char* zd = smem + 65536 + wv * 3072;
        __builtin_amdgcn_global_load_lds((const AS1 void*)zs,         (AS3 void*)zd,          16, 0, 0);
        __builtin_amdgcn_global_load_lds((const AS1 void*)(zs + 256), (AS3 void*)(zd + 1024), 16, 0, 0);
        __builtin_amdgcn_global_load_lds((const AS1 void*)(zs + 512), (AS3 void*)(zd + 2048), 16, 0, 0);
    }

    // weight fragments: wlch[g*1024 + nt*64] is this lane's half8 for (g, nt)
    const half8* wlch = (const half8*)wst + (size_t)ch * 32768 + wv * 256 + lane;

    half8 wreg[2][4];
    #pragma unroll
    for (int nt = 0; nt < 4; ++nt) wreg[0][nt] = wlch[nt * 64];  // g=0, early

    // hidden-layer bias source: lane covers n = wv*64 + nt*16 + ks*4 .. +3
    const float* bh = (isC ? bc_h : br_h) + c * 256 + wv * 64 + ks * 4;

    // B-frag base: addr(mt, kk, half) = (vbase ^ (kk<<6)) + half*32768 + mt*8192
    const int vbase = r16 * 512 + (((r16 & 7) ^ ks) << 4);

    // input-layer weights (registers)
    const int jg = tid & 31;
    const int rg = tid >> 5;
    const float* Wi = (isC ? Wc_in : Wr_in) + c * 256 + jg * 8;
    const float* bi = (isC ? bc_in : br_in) + c * 256 + jg * 8;
    float4 w0 = *(const float4*)Wi;
    float4 w1 = *(const float4*)(Wi + 4);
    float4 v0 = *(const float4*)bi;
    float4 v1 = *(const float4*)(bi + 4);

    wait_vm0();
    barrier_raw();                                  // z visible

    // ---- input layer: h0[m][j] = relu(x_m * W_in[j] + b_in[j]) ----
    {
        #pragma unroll
        for (int i = 0; i < 16; ++i) {
            int m = rg * 16 + i;
            float x;
            if (!isC) x = zbuf[m * 24 + c];
            else {
                float2 p = *(const float2*)(zbuf + m * 24 + 8 + 2 * c);
                x = p.x * p.x + p.y * p.y;
            }
            half8 o;
            o[0] = (_Float16)fmaxf(fmaf(x, w0.x, v0.x), 0.f);
            o[1] = (_Float16)fmaxf(fmaf(x, w0.y, v0.y), 0.f);
            o[2] = (_Float16)fmaxf(fmaf(x, w0.z, v0.z), 0.f);
            o[3] = (_Float16)fmaxf(fmaf(x, w0.w, v0.w), 0.f);
            o[4] = (_Float16)fmaxf(fmaf(x, w1.x, v1.x), 0.f);
            o[5] = (_Float16)fmaxf(fmaf(x, w1.y, v1.y), 0.f);
            o[6] = (_Float16)fmaxf(fmaf(x, w1.z, v1.z), 0.f);
            o[7] = (_Float16)fmaxf(fmaf(x, w1.w, v1.w), 0.f);
            *(half8*)(smem + m * 512 + ((jg ^ (m & 7)) << 4)) = o;
        }
    }
    wait_lgkm0();
    barrier_raw();                                  // h0 visible

    floatx4 accA[4][4], accB[4][4];

    // ---- P0: Kloop(A, 0), no epi ----
    run_phase<0, 1, false>(smem, vbase, wlch, wlch, bh,
                           wreg, accA, accB, wv, ks, r16);
    wait_lgkm0();
    barrier_raw();

    #pragma unroll 1
    for (int l = 0; l < 4; ++l) {
        const half8* wl_l = wlch + l * 8192;
        // phaseB(l): Kloop(B,l) ∥ epi_A(l)
        run_phase<1, 0, true>(smem, vbase, wl_l, (l < 3 ? wl_l + 8192 : wl_l),
                              bh + l * 2048, wreg, accB, accA, wv, ks, r16);
        wait_lgkm0();
        barrier_raw();
        if (l < 3) {
            // phaseA(l+1): Kloop(A,l+1) ∥ epi_B(l)
            run_phase<0, 1, true>(smem, vbase, wl_l + 8192, wl_l + 8192,
                                  bh + l * 2048, wreg, accA, accB, wv, ks, r16);
            wait_lgkm0();
            barrier_raw();
        }
    }

    // ---- P8: epi(B, 3) ----
    {
        float4 eb[4];
        #pragma unroll
        for (int nt = 0; nt < 4; ++nt) eb[nt] = *(const float4*)(bh + 3 * 2048 + nt * 16);
        #pragma unroll
        for (int u = 0; u < 16; ++u) {
            const int nt = u >> 2, mt = u & 3;
            floatx4 v = accB[nt][mt];
            float4 b = eb[nt];
            union { fp16x2 h; unsigned u32; } c0, c1;
            c0.h = __builtin_amdgcn_cvt_pkrtz(fmaxf(v[0] + b.x, 0.f), fmaxf(v[1] + b.y, 0.f));
            c1.h = __builtin_amdgcn_cvt_pkrtz(fmaxf(v[2] + b.z, 0.f), fmaxf(v[3] + b.w, 0.f));
            const int nb = wv * 64 + nt * 16 + ks * 4;
            const int m = 64 + mt * 16 + r16;
            uint2v o; o[0] = c0.u32; o[1] = c1.u32;
            *(uint2v*)(smem + m * 512 + (((nb >> 3) << 4) ^ ((r16 & 7) << 4)) + (nb & 7) * 2) = o;
        }
    }
    wait_lgkm0();
    barrier_raw();                                  // h4 complete

    // ---- output layer: 2 threads/row, fp16 packed W_out ----
    {
        const int q = tid & 1, m = tid >> 1;       // m in 0..127
        const half8* Wo = (const half8*)(wst + WOUT_OFF) + ch * 64 + q * 16;
        float s0 = 0.f, s1 = 0.f;
        #pragma unroll
        for (int i = 0; i < 16; ++i) {
            int slot = q * 16 + i;
            half8 hv = *(const half8*)(smem + m * 512 + ((slot ^ (m & 7)) << 4));
            half8 wo0 = Wo[i];
            #pragma unroll
            for (int e = 0; e < 8; ++e) s0 = fmaf((float)hv[e], (float)wo0[e], s0);
            if (isC) {
                half8 wo1 = Wo[32 + i];
                #pragma unroll
                for (int e = 0; e < 8; ++e) s1 = fmaf((float)hv[e], (float)wo1[e], s1);
            }
        }
        s0 += __shfl_xor(s0, 1);
        if (isC) s1 += __shfl_xor(s1, 1);
        if (q == 0) {
            const int row = m0 + m;
            if (!isC) {
                out[row * 8 + c] = s0 + br_out[c];
            } else {
                out[OUT_MU + row * 8 + c] = s0 + bc_out[c * 2];
                out[OUT_OM + row * 8 + c] = s1 + bc_out[c * 2 + 1];
            }
        }
    }
}

extern "C" void kernel_launch(void* const* d_in, const int* in_sizes, int n_in,
                              void* d_out, int out_size, void* d_ws, size_t ws_size,
                              hipStream_t stream) {
    const float* z      = (const float*)d_in[0];
    const float* Wr_in  = (const float*)d_in[1];
    const float* br_in  = (const float*)d_in[2];
    const float* Wr_h   = (const float*)d_in[3];
    const float* br_h   = (const float*)d_in[4];
    const float* Wr_out = (const float*)d_in[5];
    const float* br_out = (const float*)d_in[6];
    const float* Wc_in  = (const float*)d_in[7];
    const float* bc_in  = (const float*)d_in[8];
    const float* Wc_h   = (const float*)d_in[9];
    const float* bc_h   = (const float*)d_in[10];
    const float* Wc_out = (const float*)d_in[11];
    const float* bc_out = (const float*)d_in[12];
    _Float16* wst = (_Float16*)d_ws;               // 8 MB weights + wout pack
    float* out = (float*)d_out;

    prep_w<<<2048, 256, 0, stream>>>(Wr_h, Wc_h, wst);
    prep_wo<<<32, 256, 0, stream>>>(Wr_out, Wc_out, wst);
    mlp_fused<<<2048, 256, 0, stream>>>(z, Wr_in, br_in, Wc_in, bc_in,
                                        br_h, bc_h, br_out, bc_out, wst, out);
}

// Round 14
// 129.070 us; speedup vs baseline: 1.1425x; 1.1425x over previous
//
#include <hip/hip_runtime.h>

#define OUT_MU 131072
#define OUT_OM 262144
#define WOFRAG_OFF 4210688            // half-index of packed W_out MFMA fragments

typedef _Float16 half8 __attribute__((ext_vector_type(8)));
typedef __fp16   fp16x2 __attribute__((ext_vector_type(2)));
typedef float    floatx4 __attribute__((ext_vector_type(4)));
typedef unsigned uint2v __attribute__((ext_vector_type(2)));

__device__ __forceinline__ void wait_lgkm0() {
    asm volatile("s_waitcnt lgkmcnt(0)" ::: "memory");
}
__device__ __forceinline__ void wait_vm0() {
    asm volatile("s_waitcnt vmcnt(0)" ::: "memory");
}
__device__ __forceinline__ void barrier_raw() {
    asm volatile("s_barrier" ::: "memory");
}

#define AS1 __attribute__((address_space(1)))
#define AS3 __attribute__((address_space(3)))

// ---------------------------------------------------------------------------
// Repack hidden weights fp32 -> fp16 as
//   [ch(16)][g(32)][wv(4)][nt(4)][ks(4)][r16(16)][e(8)]   (half8 units)
// A-frag (16x16x32_f16): lane l holds row n = nt*16 + (l&15),
//                        k = (g&7)*32 + (l>>4)*8 + e.   (verified R4-R12)
// ---------------------------------------------------------------------------
__global__ void prep_w(const float* __restrict__ Wr_h,
                       const float* __restrict__ Wc_h,
                       _Float16* __restrict__ dst) {
    int v = blockIdx.x * 256 + threadIdx.x;        // 524288 half8 slots
    int r16 = v & 15;
    int ks  = (v >> 4) & 3;
    int nt  = (v >> 6) & 3;
    int wv  = (v >> 8) & 3;
    int g   = (v >> 10) & 31;
    int ch  = v >> 15;
    int l = g >> 3, kk = g & 7;
    int n  = wv * 64 + nt * 16 + r16;
    int k0 = kk * 32 + ks * 8;
    const float* src = (ch < 8) ? Wr_h : Wc_h;
    int c = ch & 7;
    const float* p = src + ((size_t)((l * 8 + c) * 256 + n)) * 256 + k0;
    float4 a = *(const float4*)p;
    float4 b = *(const float4*)(p + 4);
    half8 o;
    o[0] = (_Float16)a.x; o[1] = (_Float16)a.y; o[2] = (_Float16)a.z; o[3] = (_Float16)a.w;
    o[4] = (_Float16)b.x; o[5] = (_Float16)b.y; o[6] = (_Float16)b.z; o[7] = (_Float16)b.w;
    *(half8*)(dst + (size_t)v * 8) = o;
}

// W_out as MFMA A-fragments: [ch(16)][kk(8)][lane(64)] half8.
// Lane l holds A[row d = l&15][k = kk*32 + (l>>4)*8 + e]; rows >=2 are zero
// (real channels: row 1 also zero).
__global__ void prep_wof(const float* __restrict__ Wr_out,
                         const float* __restrict__ Wc_out,
                         _Float16* __restrict__ dst) {
    int t = blockIdx.x * 256 + threadIdx.x;        // 8192 half8 slots
    int lane = t & 63;
    int kk   = (t >> 6) & 7;
    int ch   = t >> 9;
    int c = ch & 7, d = lane & 15;
    int k0 = kk * 32 + (lane >> 4) * 8;
    half8 o;
    #pragma unroll
    for (int e = 0; e < 8; ++e) {
        int k = k0 + e;
        float v = 0.f;
        if (ch < 8) { if (d == 0) v = Wr_out[c * 256 + k]; }
        else        { if (d < 2)  v = Wc_out[(c * 2 + d) * 256 + k]; }
        o[e] = (_Float16)v;
    }
    *(half8*)(dst + WOFRAG_OFF + (size_t)t * 8) = o;
}

// ---------------------------------------------------------------------------
// Fused MLP, 16x16x32_f16, 4 waves, 128-row tile (R12 structure) with the
// output layer converted to MFMA (16 MFMA/wave + 4-wave LDS reduce) instead
// of ~700 scalar VALU ops/thread.
// ---------------------------------------------------------------------------
__global__ __launch_bounds__(256, 2)
void mlp_fused(const float* __restrict__ z,
               const float* __restrict__ Wr_in, const float* __restrict__ br_in,
               const float* __restrict__ Wc_in, const float* __restrict__ bc_in,
               const float* __restrict__ br_h,  const float* __restrict__ bc_h,
               const float* __restrict__ br_out, const float* __restrict__ bc_out,
               const _Float16* __restrict__ wst,
               float* __restrict__ out) {
    __shared__ __align__(16) char smem[77824];     // [0,64K)=h, [64K,76K)=z/reduce
    const int tid  = threadIdx.x;
    const int lane = tid & 63;
    const int wv   = tid >> 6;
    const int bid  = blockIdx.x;
    const int ch   = bid & 15;
    const int m0   = (bid >> 4) * 128;
    const bool isC = ch >= 8;
    const int c    = ch & 7;
    const int ks   = lane >> 4;
    const int r16  = lane & 15;
    float* zbuf = (float*)(smem + 65536);

    // ---- stage z tile (wave wv stages rows [wv*32, wv*32+32)) ----
    {
        const float* zs = z + (size_t)m0 * 24 + wv * 768 + lane * 4;
        char* zd = smem + 65536 + wv * 3072;
        __builtin_amdgcn_global_load_lds((const AS1 void*)zs,         (AS3 void*)zd,          16, 0, 0);
        __builtin_amdgcn_global_load_lds((const AS1 void*)(zs + 256), (AS3 void*)(zd + 1024), 16, 0, 0);
        __builtin_amdgcn_global_load_lds((const AS1 void*)(zs + 512), (AS3 void*)(zd + 2048), 16, 0, 0);
    }

    // weight fragments: wl[g*1024 + nt*64] is this lane's half8 for (g, nt)
    const half8* wl = (const half8*)wst + (size_t)ch * 32768 + wv * 256 + lane;

    half8 wr2[2][4];
    #pragma unroll
    for (int nt = 0; nt < 4; ++nt) wr2[0][nt] = wl[nt * 64];  // g = 0, issued early

    // hidden-layer bias source: lane needs n = wv*64 + nt*16 + ks*4 (float4)
    const float* bh = (isC ? bc_h : br_h) + c * 256 + wv * 64 + ks * 4;

    // B-frag base: addr(mt, kk) = (vbase ^ (kk<<6)) + mt*8192
    const int vbase = r16 * 512 + (((r16 & 7) ^ ks) << 4);

    // input-layer weights (registers)
    const int jg = tid & 31;                       // slot j0 = jg*8
    const int rg = tid >> 5;                       // rows rg*16 .. rg*16+15
    const float* Wi = (isC ? Wc_in : Wr_in) + c * 256 + jg * 8;
    const float* bi = (isC ? bc_in : br_in) + c * 256 + jg * 8;
    float4 w0 = *(const float4*)Wi;
    float4 w1 = *(const float4*)(Wi + 4);
    float4 v0 = *(const float4*)bi;
    float4 v1 = *(const float4*)(bi + 4);

    wait_vm0();                                     // z tile + wr2[0] + Wi/bi landed
    barrier_raw();                                  // z visible to all waves

    // ---- input layer: h0[m][j] = relu(x_m * W_in[j] + b_in[j]) ----
    {
        #pragma unroll
        for (int i = 0; i < 16; ++i) {
            int m = rg * 16 + i;
            float x;
            if (!isC) x = zbuf[m * 24 + c];
            else {
                float2 p = *(const float2*)(zbuf + m * 24 + 8 + 2 * c);
                x = p.x * p.x + p.y * p.y;
            }
            half8 o;
            o[0] = (_Float16)fmaxf(fmaf(x, w0.x, v0.x), 0.f);
            o[1] = (_Float16)fmaxf(fmaf(x, w0.y, v0.y), 0.f);
            o[2] = (_Float16)fmaxf(fmaf(x, w0.z, v0.z), 0.f);
            o[3] = (_Float16)fmaxf(fmaf(x, w0.w, v0.w), 0.f);
            o[4] = (_Float16)fmaxf(fmaf(x, w1.x, v1.x), 0.f);
            o[5] = (_Float16)fmaxf(fmaf(x, w1.y, v1.y), 0.f);
            o[6] = (_Float16)fmaxf(fmaf(x, w1.z, v1.z), 0.f);
            o[7] = (_Float16)fmaxf(fmaf(x, w1.w, v1.w), 0.f);
            *(half8*)(smem + m * 512 + ((jg ^ (m & 7)) << 4)) = o;
        }
    }
    wait_lgkm0();
    barrier_raw();                                  // h0 visible

    #pragma unroll 1
    for (int l = 0; l < 4; ++l) {
        // bias for this layer: 4 aligned float4 loads (contiguous n per lane)
        float4 bnt[4];
        #pragma unroll
        for (int nt = 0; nt < 4; ++nt)
            bnt[nt] = *(const float4*)(bh + l * 2048 + nt * 16);

        floatx4 acc[4][8];
        #pragma unroll
        for (int nt = 0; nt < 4; ++nt) {
            floatx4 bi4;
            bi4[0] = bnt[nt].x; bi4[1] = bnt[nt].y;
            bi4[2] = bnt[nt].z; bi4[3] = bnt[nt].w;
            #pragma unroll
            for (int mt = 0; mt < 8; ++mt) acc[nt][mt] = bi4;  // bias-init
        }

        half8 bfr[3][4];
        {   // layer prologue: hs=0 (kk=0, mt 0-3) and hs=1 (kk=0, mt 4-7)
            const char* b0 = smem + vbase;
            #pragma unroll
            for (int j = 0; j < 4; ++j) bfr[0][j] = *(const half8*)(b0 + j * 8192);
            #pragma unroll
            for (int j = 0; j < 4; ++j) bfr[1][j] = *(const half8*)(b0 + 32768 + j * 8192);
        }

        #pragma unroll
        for (int hs = 0; hs < 16; ++hs) {
            const int kk = hs >> 1, half = hs & 1;
            if (half == 0) {                        // weight prefetch for kk+1
                const half8* p = wl + (size_t)(kk + 1) * 1024;
                #pragma unroll
                for (int nt = 0; nt < 4; ++nt) wr2[(kk + 1) & 1][nt] = p[nt * 64];
            }
            if (hs < 14) {                          // activation prefetch, depth 2
                const int nhs = hs + 2;
                const char* nb = smem + (vbase ^ ((nhs >> 1) << 6)) + (nhs & 1) * 32768;
                #pragma unroll
                for (int j = 0; j < 4; ++j)
                    bfr[nhs % 3][j] = *(const half8*)(nb + j * 8192);
            }
            __builtin_amdgcn_s_setprio(1);
            #pragma unroll
            for (int nt = 0; nt < 4; ++nt)
                #pragma unroll
                for (int j = 0; j < 4; ++j)
                    acc[nt][half * 4 + j] = __builtin_amdgcn_mfma_f32_16x16x32_f16(
                        wr2[kk & 1][nt], bfr[hs % 3][j], acc[nt][half * 4 + j], 0, 0, 0);
            __builtin_amdgcn_s_setprio(0);
        }
        wl += 8192;                                 // next layer's weights

        // ---- layer epilogue: relu + packed cvt -> h (bias already in acc) ----
        wait_lgkm0();
        barrier_raw();                              // all reads of layer l done
        #pragma unroll
        for (int nt = 0; nt < 4; ++nt) {
            const int nb = wv * 64 + nt * 16 + ks * 4;
            const int sw = ((nb >> 3) << 4);
            #pragma unroll
            for (int mt = 0; mt < 8; ++mt) {
                const int m = mt * 16 + r16;
                floatx4 v = acc[nt][mt];
                union { fp16x2 h; unsigned u; } c0, c1;
                c0.h = __builtin_amdgcn_cvt_pkrtz(fmaxf(v[0], 0.f), fmaxf(v[1], 0.f));
                c1.h = __builtin_amdgcn_cvt_pkrtz(fmaxf(v[2], 0.f), fmaxf(v[3], 0.f));
                uint2v o; o[0] = c0.u; o[1] = c1.u;
                *(uint2v*)(smem + m * 512 + (sw ^ ((m & 7) << 4)) + (nb & 7) * 2) = o;
            }
        }
        wait_lgkm0();
        barrier_raw();                              // new h visible
    }

    // ---- output layer via MFMA: out_d = W_out[d] . h4 ----
    {
        const half8* wof = (const half8*)(wst + WOFRAG_OFF) + ch * 512 + lane;
        floatx4 acco[8];
        #pragma unroll
        for (int mt = 0; mt < 8; ++mt) acco[mt] = 0.f;
        #pragma unroll
        for (int q = 0; q < 2; ++q) {
            const int kk = 2 * wv + q;              // each wave covers 2 K-slices
            half8 a = wof[kk * 64];
            #pragma unroll
            for (int mt = 0; mt < 8; ++mt) {
                half8 bf = *(const half8*)(smem + (vbase ^ (kk << 6)) + mt * 8192);
                acco[mt] = __builtin_amdgcn_mfma_f32_16x16x32_f16(a, bf, acco[mt], 0, 0, 0);
            }
        }
        // D rows 0,1 (d=0,1) live in lanes 0..15, regs 0,1; col m = mt*16 + lane
        float2* zb2 = (float2*)(smem + 65536);      // reuse retired z region (4 KB)
        if (lane < 16) {
            #pragma unroll
            for (int mt = 0; mt < 8; ++mt) {
                float2 p; p.x = acco[mt][0]; p.y = acco[mt][1];
                zb2[wv * 128 + mt * 16 + lane] = p;
            }
        }
        wait_lgkm0();
        barrier_raw();                              // partials visible
        if (tid < 128) {
            const int m = tid;
            float2 a0 = zb2[m],       a1 = zb2[128 + m];
            float2 a2 = zb2[256 + m], a3 = zb2[384 + m];
            float s0 = (a0.x + a1.x) + (a2.x + a3.x);
            const int row = m0 + m;
            if (!isC) {
                out[row * 8 + c] = s0 + br_out[c];
            } else {
                float s1 = (a0.y + a1.y) + (a2.y + a3.y);
                out[OUT_MU + row * 8 + c] = s0 + bc_out[c * 2];
                out[OUT_OM + row * 8 + c] = s1 + bc_out[c * 2 + 1];
            }
        }
    }
}

extern "C" void kernel_launch(void* const* d_in, const int* in_sizes, int n_in,
                              void* d_out, int out_size, void* d_ws, size_t ws_size,
                              hipStream_t stream) {
    const float* z      = (const float*)d_in[0];
    const float* Wr_in  = (const float*)d_in[1];
    const float* br_in  = (const float*)d_in[2];
    const float* Wr_h   = (const float*)d_in[3];
    const float* br_h   = (const float*)d_in[4];
    const float* Wr_out = (const float*)d_in[5];
    const float* br_out = (const float*)d_in[6];
    const float* Wc_in  = (const float*)d_in[7];
    const float* bc_in  = (const float*)d_in[8];
    const float* Wc_h   = (const float*)d_in[9];
    const float* bc_h   = (const float*)d_in[10];
    const float* Wc_out = (const float*)d_in[11];
    const float* bc_out = (const float*)d_in[12];
    _Float16* wst = (_Float16*)d_ws;               // 8 MB weights + wout frag pack
    float* out = (float*)d_out;

    prep_w<<<2048, 256, 0, stream>>>(Wr_h, Wc_h, wst);
    prep_wof<<<32, 256, 0, stream>>>(Wr_out, Wc_out, wst);
    mlp_fused<<<2048, 256, 0, stream>>>(z, Wr_in, br_in, Wc_in, bc_in,
                                        br_h, bc_h, br_out, bc_out, wst, out);
}